// Round 13
// baseline (185.480 us; speedup 1.0000x reference)
//
#include <hip/hip_runtime.h>

#define NN 4096
#define DD 2048
#define MARGIN_F 0.3f
#define NT64 (NN / 64)     // 64 row-blocks of 64
#define NTILES 2080        // 64*65/2 upper-triangular 64x64 tiles
#define BK 256             // K bytes per stage
#define NIT (DD / BK)      // 8
#define QS (127.0f / 6.0f)
#define C2 (2.0f * (6.0f / 127.0f) * (6.0f / 127.0f))  // 2/QS^2

typedef __attribute__((ext_vector_type(4))) int i32x4;

__device__ __forceinline__ unsigned q8(float v) {
    int i = __float2int_rn(v * QS);
    i = min(127, max(-127, i));
    return (unsigned)(i & 255);
}

// 1024 blocks x 4 waves; each wave quantizes one row (int8) + fp32
// sum-of-squares; init ap/an/counter.
__global__ __launch_bounds__(256) void prep_kernel(const float* __restrict__ x,
                                                   unsigned char* __restrict__ xq,
                                                   float* __restrict__ sq,
                                                   unsigned int* __restrict__ ap,
                                                   unsigned int* __restrict__ an,
                                                   int* __restrict__ counter) {
    const int wave = threadIdx.x >> 6, lane = threadIdx.x & 63;
    const int row = blockIdx.x * 4 + wave;
    const float* xr = x + (size_t)row * DD;
    unsigned int* orow = (unsigned int*)(xq + (size_t)row * DD);
    float s = 0.0f;
#pragma unroll
    for (int j = 0; j < 8; ++j) {
        float4 v = ((const float4*)xr)[j * 64 + lane];
        s += v.x * v.x + v.y * v.y + v.z * v.z + v.w * v.w;
        orow[j * 64 + lane] = q8(v.x) | (q8(v.y) << 8) | (q8(v.z) << 16) | (q8(v.w) << 24);
    }
    for (int off = 32; off > 0; off >>= 1) s += __shfl_down(s, off, 64);
    if (lane == 0) {
        sq[row] = s;
        ap[row] = 0u;            // hardest-positive max starts at 0
        an[row] = 0x7F800000u;   // +inf
    }
    if (threadIdx.x == 0 && blockIdx.x == 0) counter[0] = 0;
}

// Symmetric batch-hard GEMM, int8, MAX-RESIDENCY config: 2080 triangular
// 64x64 tiles, BK=256, LDS 32 KB -> 5 blocks/CU resident (20 waves/CU,
// highest of any round) with 8.1 blocks/CU available (smooth tail). The
// R1-R12 data shows runtime tracks resident-wave latency coverage, not
// bytes/BK/barrier count (m97 sustains 21.8 B/cyc/CU across 128 barriers
// at 3-4 blk/CU; R11 gets 9.3 at ~1.5 avg). Single-buffer 2-barrier
// K-loop (all dbuf variants regressed: R5/R10/R12). XOR swizzle
// col^(row&15) -> free 2-way bank aliasing only. mfma_i32_16x16x64_i8,
// wave = 64 rows x 16 cols (4x1 frags). Both-side epilogues (idempotent
// max/min, gi!=gj guards diagonal); fused last-block finalize.
__global__ __launch_bounds__(256) void gemm_reduce_kernel(
    const unsigned char* __restrict__ xq,
    const float* __restrict__ sq,
    const int* __restrict__ labels,
    unsigned int* __restrict__ ap,
    unsigned int* __restrict__ an,
    int* __restrict__ counter,
    float* __restrict__ out) {
    __shared__ __align__(16) unsigned char As[64 * BK];   // 16 KB
    __shared__ __align__(16) unsigned char Bs[64 * BK];   // 16 KB

    // decode upper-triangular 64x64 tile (bi <= bj)
    int rem = blockIdx.x;
    int bi = 0;
    while (rem >= NT64 - bi) { rem -= NT64 - bi; ++bi; }
    const int bj = bi + rem;
    const int row0 = bi * 64;
    const int col0 = bj * 64;
    const int phase = blockIdx.x & (NIT - 1);  // K-start stagger (int = exact)

    const int t = threadIdx.x;
    const int lane = t & 63;
    const int wave = t >> 6;
    const int c = lane & 15;   // fragment column lane
    const int q = lane >> 4;   // k-quad
    const int wc = wave * 16;  // wave col offset (rows shared by all waves)

    i32x4 acc[4];
#pragma unroll
    for (int mi = 0; mi < 4; ++mi) acc[mi] = (i32x4){0, 0, 0, 0};

    // Staging: rows are 256 B = 16 chunks of 16 B. Each tile 64 rows =
    // 1024 chunks (4/thread). Chunk ci = t + 256*s: row = (t>>4) + 16*s,
    // col = t&15; source col XOR-swizzled (col ^ (row&15)), s-invariant.
    const int rowb = t >> 4;
    const int colsw = (t & 15) ^ (rowb & 15);
    const unsigned char* gA[4];
    const unsigned char* gB[4];
#pragma unroll
    for (int s = 0; s < 4; ++s) {
        gA[s] = xq + (size_t)(row0 + rowb + 16 * s) * DD + colsw * 16;
        gB[s] = xq + (size_t)(col0 + rowb + 16 * s) * DD + colsw * 16;
    }

    for (int it = 0; it < NIT; ++it) {
        const int k0 = ((it + phase) & (NIT - 1)) * BK;
#pragma unroll
        for (int s = 0; s < 4; ++s)
            __builtin_amdgcn_global_load_lds(
                (const __attribute__((address_space(1))) void*)(gA[s] + k0),
                (__attribute__((address_space(3))) void*)&As[(t + 256 * s) * 16],
                16, 0, 0);
#pragma unroll
        for (int s = 0; s < 4; ++s)
            __builtin_amdgcn_global_load_lds(
                (const __attribute__((address_space(1))) void*)(gB[s] + k0),
                (__attribute__((address_space(3))) void*)&Bs[(t + 256 * s) * 16],
                16, 0, 0);
        __syncthreads();

        const i32x4* Av = (const i32x4*)As;
        const i32x4* Bv = (const i32x4*)Bs;
#pragma unroll
        for (int ks = 0; ks < 4; ++ks) {
            const int kc = q + 4 * ks;  // k-chunk for this lane's fragment
            i32x4 af[4], bf;
#pragma unroll
            for (int mi = 0; mi < 4; ++mi) {
                const int r = mi * 16 + c;
                af[mi] = Av[r * 16 + (kc ^ (r & 15))];
            }
            {
                const int r = wc + c;
                bf = Bv[r * 16 + (kc ^ (r & 15))];
            }
#pragma unroll
            for (int mi = 0; mi < 4; ++mi)
                acc[mi] = __builtin_amdgcn_mfma_i32_16x16x64_i8(
                    af[mi], bf, acc[mi], 0, 0, 0);
        }
        __syncthreads();
    }

    // --- Epilogue ---
    // C/D layout 16x16: col = lane&15 (c), row = q*4 + reg [m89/m91;
    // dtype-independent m121-m128]. This lane's column: gj = col0+wc+c.
    const int gj0 = col0 + wc + c;
    const float sq_col = sq[gj0];
    const int lab_col = labels[gj0];
    int lab_row[4][4];
    float dist[4][4];
#pragma unroll
    for (int mi = 0; mi < 4; ++mi) {
#pragma unroll
        for (int r = 0; r < 4; ++r) {
            const int gi = row0 + mi * 16 + q * 4 + r;
            lab_row[mi][r] = labels[gi];
            float d2 = sq[gi] + sq_col - C2 * (float)acc[mi][r];
            dist[mi][r] = sqrtf(fmaxf(d2, 0.0f));
        }
    }

    // Row-side: rows gi vs this wave's 16 columns (fold across the 16
    // c-lanes of each q-group).
#pragma unroll
    for (int mi = 0; mi < 4; ++mi) {
#pragma unroll
        for (int r = 0; r < 4; ++r) {
            const int gi = row0 + mi * 16 + q * 4 + r;
            const int li = lab_row[mi][r];
            float apm = 0.0f;
            float anm = __builtin_inff();
            const float d = dist[mi][r];
            if (li == lab_col) {
                if (gi != gj0) apm = d;  // exclude diagonal
            } else {
                anm = d;
            }
#pragma unroll
            for (int off = 1; off < 16; off <<= 1) {
                apm = fmaxf(apm, __shfl_xor(apm, off, 16));
                anm = fminf(anm, __shfl_xor(anm, off, 16));
            }
            if (c == 0) {
                atomicMax(&ap[gi], __float_as_uint(apm));
                atomicMin(&an[gi], __float_as_uint(anm));
            }
        }
    }

    // Column-side (transposed): this lane's column gj0 vs its 16 rows
    // (q-group rows), fold across the 4 q-groups (lanes 16 apart).
    {
        float apm = 0.0f;
        float anm = __builtin_inff();
#pragma unroll
        for (int mi = 0; mi < 4; ++mi) {
#pragma unroll
            for (int r = 0; r < 4; ++r) {
                const int gi = row0 + mi * 16 + q * 4 + r;
                const float d = dist[mi][r];
                if (lab_col == lab_row[mi][r]) {
                    if (gi != gj0) apm = fmaxf(apm, d);  // exclude diagonal
                } else {
                    anm = fminf(anm, d);
                }
            }
        }
        apm = fmaxf(apm, __shfl_xor(apm, 16, 64));
        anm = fminf(anm, __shfl_xor(anm, 16, 64));
        apm = fmaxf(apm, __shfl_xor(apm, 32, 64));
        anm = fminf(anm, __shfl_xor(anm, 32, 64));
        if (q == 0) {
            atomicMax(&ap[gj0], __float_as_uint(apm));
            atomicMin(&an[gj0], __float_as_uint(anm));
        }
    }

    // --- Fused finalize: last block to finish reduces the loss ---
    __syncthreads();  // drains this block's atomics before counter release
    int* flag = (int*)As;
    if (t == 0) {
        int old = __hip_atomic_fetch_add(counter, 1, __ATOMIC_ACQ_REL,
                                         __HIP_MEMORY_SCOPE_AGENT);
        flag[0] = (old == NTILES - 1) ? 1 : 0;
    }
    __syncthreads();
    if (flag[0]) {
        float sum = 0.0f;
        int cnt = 0;
        for (int i = t; i < NN; i += 256) {
            const float a = __uint_as_float(__hip_atomic_load(
                &ap[i], __ATOMIC_RELAXED, __HIP_MEMORY_SCOPE_AGENT));
            const float b = __uint_as_float(__hip_atomic_load(
                &an[i], __ATOMIC_RELAXED, __HIP_MEMORY_SCOPE_AGENT));
            if ((a > 0.0f) && (b < __builtin_inff())) {
                sum += fmaxf(a - b + MARGIN_F, 0.0f);
                cnt += 1;
            }
        }
        for (int off = 32; off > 0; off >>= 1) {
            sum += __shfl_down(sum, off, 64);
            cnt += __shfl_down(cnt, off, 64);
        }
        float* ssum = (float*)Bs;
        int* scnt = (int*)Bs + 8;
        if (lane == 0) { ssum[wave] = sum; scnt[wave] = cnt; }
        __syncthreads();
        if (t == 0) {
            float s = 0.0f; int n = 0;
#pragma unroll
            for (int w = 0; w < 4; ++w) { s += ssum[w]; n += scnt[w]; }
            out[0] = (n > 0) ? s / (float)n : 0.0f;
        }
    }
}

extern "C" void kernel_launch(void* const* d_in, const int* in_sizes, int n_in,
                              void* d_out, int out_size, void* d_ws, size_t ws_size,
                              hipStream_t stream) {
    const float* x = (const float*)d_in[0];
    const int* labels = (const int*)d_in[1];
    float* out = (float*)d_out;

    char* ws = (char*)d_ws;
    unsigned char* xq = (unsigned char*)ws;                         // 4096*2048 B
    float* sq = (float*)(ws + (size_t)NN * DD);
    unsigned int* ap = (unsigned int*)(ws + (size_t)NN * DD + (size_t)NN * 4);
    unsigned int* an = (unsigned int*)(ws + (size_t)NN * DD + (size_t)NN * 8);
    int* counter = (int*)(ws + (size_t)NN * DD + (size_t)NN * 12);

    prep_kernel<<<NN / 4, 256, 0, stream>>>(x, xq, sq, ap, an, counter);
    gemm_reduce_kernel<<<NTILES, 256, 0, stream>>>(xq, sq, labels, ap, an, counter, out);
}

// Round 14
// 142.179 us; speedup vs baseline: 1.3046x; 1.3046x over previous
//
#include <hip/hip_runtime.h>

#define NN 4096
#define DD 2048
#define MARGIN_F 0.3f
#define NTILES 1056  // 64x128 tiles covering the upper triangle (dupes OK)
#define BK 256       // K bytes per stage
#define NIT (DD / BK)  // 8
#define QS (127.0f / 6.0f)
#define C2 (2.0f * (6.0f / 127.0f) * (6.0f / 127.0f))  // 2/QS^2

typedef __attribute__((ext_vector_type(4))) int i32x4;

__device__ __forceinline__ unsigned q8(float v) {
    int i = __float2int_rn(v * QS);
    i = min(127, max(-127, i));
    return (unsigned)(i & 255);
}

// 1024 blocks x 4 waves; each wave quantizes one row (int8) + fp32
// sum-of-squares; init ap/an/counter.
__global__ __launch_bounds__(256) void prep_kernel(const float* __restrict__ x,
                                                   unsigned char* __restrict__ xq,
                                                   float* __restrict__ sq,
                                                   unsigned int* __restrict__ ap,
                                                   unsigned int* __restrict__ an,
                                                   int* __restrict__ counter) {
    const int wave = threadIdx.x >> 6, lane = threadIdx.x & 63;
    const int row = blockIdx.x * 4 + wave;
    const float* xr = x + (size_t)row * DD;
    unsigned int* orow = (unsigned int*)(xq + (size_t)row * DD);
    float s = 0.0f;
#pragma unroll
    for (int j = 0; j < 8; ++j) {
        float4 v = ((const float4*)xr)[j * 64 + lane];
        s += v.x * v.x + v.y * v.y + v.z * v.z + v.w * v.w;
        orow[j * 64 + lane] = q8(v.x) | (q8(v.y) << 8) | (q8(v.z) << 16) | (q8(v.w) << 24);
    }
    for (int off = 32; off > 0; off >>= 1) s += __shfl_down(s, off, 64);
    if (lane == 0) {
        sq[row] = s;
        ap[row] = 0u;            // hardest-positive max starts at 0
        an[row] = 0x7F800000u;   // +inf
    }
    if (threadIdx.x == 0 && blockIdx.x == 0) counter[0] = 0;
}

// BEST-KNOWN CONFIG (R11, 141.5 us total / 71.2 us GEMM): symmetric
// batch-hard GEMM, int8, 1056 x (64x128) triangular tiles, BK=256 (NIT=8),
// LDS 48 KB -> 3 blocks/CU. Single-buffer 2-barrier K-loop — all dbuf /
// producer-consumer / LDS-free variants regressed (R5/R9/R10/R12); the
// residual per-iteration cost is the exposed L2 round-trip + barrier drain
// (m97-structure plateau), not addressable at HIP source level (m131-m141).
// XOR swizzle col^(row&15) -> free 2-way bank aliasing only (0 conflicts).
// mfma_i32_16x16x64_i8, wave = 64 rows x 32 cols (4x2 frags), 4 k-chunks
// per stage. Both-side epilogues (idempotent max/min; gi!=gj guards the
// diagonal); fused last-block finalize; K-phase stagger (int = exact).
__global__ __launch_bounds__(256) void gemm_reduce_kernel(
    const unsigned char* __restrict__ xq,
    const float* __restrict__ sq,
    const int* __restrict__ labels,
    unsigned int* __restrict__ ap,
    unsigned int* __restrict__ an,
    int* __restrict__ counter,
    float* __restrict__ out) {
    __shared__ __align__(16) unsigned char As[64 * BK];    // 16 KB
    __shared__ __align__(16) unsigned char Bs[128 * BK];   // 32 KB

    // decode tile: row-block mi64 (64 rows), col-block nj (128 cols),
    // tiles with 128*nj + 127 >= 64*mi64, i.e. nj >= floor(mi64/2).
    int rem = blockIdx.x;
    int mi64 = 0;
    while (rem >= 32 - (mi64 >> 1)) { rem -= 32 - (mi64 >> 1); ++mi64; }
    const int nj = (mi64 >> 1) + rem;
    const int row0 = mi64 * 64;
    const int col0 = nj * 128;
    const int phase = blockIdx.x & (NIT - 1);  // K-start stagger

    const int t = threadIdx.x;
    const int lane = t & 63;
    const int wave = t >> 6;
    const int c = lane & 15;   // fragment column lane
    const int q = lane >> 4;   // k-quad
    const int wc = wave * 32;  // wave col offset (rows shared by all waves)

    i32x4 acc[4][2];
#pragma unroll
    for (int mi = 0; mi < 4; ++mi)
#pragma unroll
        for (int ni = 0; ni < 2; ++ni)
            acc[mi][ni] = (i32x4){0, 0, 0, 0};

    // Staging: rows are 256 B = 16 chunks of 16 B. A tile 64 rows = 1024
    // chunks (4/thread), B tile 128 rows = 2048 chunks (8/thread).
    // Chunk ci = t + 256*s: row = (t>>4) + 16*s, col = t&15; source col
    // XOR-swizzled (col ^ (row&15)), s-invariant.
    const int rowb = t >> 4;
    const int colsw = (t & 15) ^ (rowb & 15);
    const unsigned char* gA[4];
    const unsigned char* gB[8];
#pragma unroll
    for (int s = 0; s < 4; ++s)
        gA[s] = xq + (size_t)(row0 + rowb + 16 * s) * DD + colsw * 16;
#pragma unroll
    for (int s = 0; s < 8; ++s)
        gB[s] = xq + (size_t)(col0 + rowb + 16 * s) * DD + colsw * 16;

    for (int it = 0; it < NIT; ++it) {
        const int k0 = ((it + phase) & (NIT - 1)) * BK;
#pragma unroll
        for (int s = 0; s < 4; ++s)
            __builtin_amdgcn_global_load_lds(
                (const __attribute__((address_space(1))) void*)(gA[s] + k0),
                (__attribute__((address_space(3))) void*)&As[(t + 256 * s) * 16],
                16, 0, 0);
#pragma unroll
        for (int s = 0; s < 8; ++s)
            __builtin_amdgcn_global_load_lds(
                (const __attribute__((address_space(1))) void*)(gB[s] + k0),
                (__attribute__((address_space(3))) void*)&Bs[(t + 256 * s) * 16],
                16, 0, 0);
        __syncthreads();

        const i32x4* Av = (const i32x4*)As;
        const i32x4* Bv = (const i32x4*)Bs;
#pragma unroll
        for (int ks = 0; ks < 4; ++ks) {
            const int kc = q + 4 * ks;  // k-chunk for this lane's fragment
            i32x4 af[4], bfr[2];
#pragma unroll
            for (int mi = 0; mi < 4; ++mi) {
                const int r = mi * 16 + c;
                af[mi] = Av[r * 16 + (kc ^ (r & 15))];
            }
#pragma unroll
            for (int ni = 0; ni < 2; ++ni) {
                const int r = wc + ni * 16 + c;
                bfr[ni] = Bv[r * 16 + (kc ^ (r & 15))];
            }
#pragma unroll
            for (int mi = 0; mi < 4; ++mi)
#pragma unroll
                for (int ni = 0; ni < 2; ++ni)
                    acc[mi][ni] = __builtin_amdgcn_mfma_i32_16x16x64_i8(
                        af[mi], bfr[ni], acc[mi][ni], 0, 0, 0);
        }
        __syncthreads();
    }

    // --- Epilogue ---
    // C/D layout 16x16: col = lane&15 (c), row = q*4 + reg [m89/m91;
    // dtype-independent m121-m128]
    float sq_col[2];
    int lab_col[2];
#pragma unroll
    for (int ni = 0; ni < 2; ++ni) {
        const int gj = col0 + wc + ni * 16 + c;
        sq_col[ni] = sq[gj];
        lab_col[ni] = labels[gj];
    }
    int lab_row[4][4];
    float dist[4][2][4];
#pragma unroll
    for (int mi = 0; mi < 4; ++mi) {
#pragma unroll
        for (int r = 0; r < 4; ++r) {
            const int gi = row0 + mi * 16 + q * 4 + r;
            const float sqi = sq[gi];
            lab_row[mi][r] = labels[gi];
#pragma unroll
            for (int ni = 0; ni < 2; ++ni) {
                float d2 = sqi + sq_col[ni] - C2 * (float)acc[mi][ni][r];
                dist[mi][ni][r] = sqrtf(fmaxf(d2, 0.0f));
            }
        }
    }

    // Row-side: rows gi vs this wave's 32 columns.
#pragma unroll
    for (int mi = 0; mi < 4; ++mi) {
#pragma unroll
        for (int r = 0; r < 4; ++r) {
            const int gi = row0 + mi * 16 + q * 4 + r;
            const int li = lab_row[mi][r];
            float apm = 0.0f;
            float anm = __builtin_inff();
#pragma unroll
            for (int ni = 0; ni < 2; ++ni) {
                const int gj = col0 + wc + ni * 16 + c;
                const float d = dist[mi][ni][r];
                if (li == lab_col[ni]) {
                    if (gi != gj) apm = fmaxf(apm, d);  // exclude diagonal
                } else {
                    anm = fminf(anm, d);
                }
            }
#pragma unroll
            for (int off = 1; off < 16; off <<= 1) {
                apm = fmaxf(apm, __shfl_xor(apm, off, 16));
                anm = fminf(anm, __shfl_xor(anm, off, 16));
            }
            if (c == 0) {
                atomicMax(&ap[gi], __float_as_uint(apm));
                atomicMin(&an[gi], __float_as_uint(anm));
            }
        }
    }

    // Column-side (transposed): S(gi,gj) also serves row gj (dupes
    // idempotent; diagonal guarded).
#pragma unroll
    for (int ni = 0; ni < 2; ++ni) {
        const int gj = col0 + wc + ni * 16 + c;
        const int lj = lab_col[ni];
        float apm = 0.0f;
        float anm = __builtin_inff();
#pragma unroll
        for (int mi = 0; mi < 4; ++mi) {
#pragma unroll
            for (int r = 0; r < 4; ++r) {
                const int gi = row0 + mi * 16 + q * 4 + r;
                const float d = dist[mi][ni][r];
                if (lj == lab_row[mi][r]) {
                    if (gi != gj) apm = fmaxf(apm, d);  // exclude diagonal
                } else {
                    anm = fminf(anm, d);
                }
            }
        }
        apm = fmaxf(apm, __shfl_xor(apm, 16, 64));
        anm = fminf(anm, __shfl_xor(anm, 16, 64));
        apm = fmaxf(apm, __shfl_xor(apm, 32, 64));
        anm = fminf(anm, __shfl_xor(anm, 32, 64));
        if (q == 0) {
            atomicMax(&ap[gj], __float_as_uint(apm));
            atomicMin(&an[gj], __float_as_uint(anm));
        }
    }

    // --- Fused finalize: last block to finish reduces the loss ---
    __syncthreads();  // drains this block's atomics before counter release
    int* flag = (int*)As;
    if (t == 0) {
        int old = __hip_atomic_fetch_add(counter, 1, __ATOMIC_ACQ_REL,
                                         __HIP_MEMORY_SCOPE_AGENT);
        flag[0] = (old == NTILES - 1) ? 1 : 0;
    }
    __syncthreads();
    if (flag[0]) {
        float sum = 0.0f;
        int cnt = 0;
        for (int i = t; i < NN; i += 256) {
            const float a = __uint_as_float(__hip_atomic_load(
                &ap[i], __ATOMIC_RELAXED, __HIP_MEMORY_SCOPE_AGENT));
            const float b = __uint_as_float(__hip_atomic_load(
                &an[i], __ATOMIC_RELAXED, __HIP_MEMORY_SCOPE_AGENT));
            if ((a > 0.0f) && (b < __builtin_inff())) {
                sum += fmaxf(a - b + MARGIN_F, 0.0f);
                cnt += 1;
            }
        }
        for (int off = 32; off > 0; off >>= 1) {
            sum += __shfl_down(sum, off, 64);
            cnt += __shfl_down(cnt, off, 64);
        }
        float* ssum = (float*)Bs;
        int* scnt = (int*)Bs + 8;
        if (lane == 0) { ssum[wave] = sum; scnt[wave] = cnt; }
        __syncthreads();
        if (t == 0) {
            float s = 0.0f; int n = 0;
#pragma unroll
            for (int w = 0; w < 4; ++w) { s += ssum[w]; n += scnt[w]; }
            out[0] = (n > 0) ? s / (float)n : 0.0f;
        }
    }
}

extern "C" void kernel_launch(void* const* d_in, const int* in_sizes, int n_in,
                              void* d_out, int out_size, void* d_ws, size_t ws_size,
                              hipStream_t stream) {
    const float* x = (const float*)d_in[0];
    const int* labels = (const int*)d_in[1];
    float* out = (float*)d_out;

    char* ws = (char*)d_ws;
    unsigned char* xq = (unsigned char*)ws;                         // 4096*2048 B
    float* sq = (float*)(ws + (size_t)NN * DD);
    unsigned int* ap = (unsigned int*)(ws + (size_t)NN * DD + (size_t)NN * 4);
    unsigned int* an = (unsigned int*)(ws + (size_t)NN * DD + (size_t)NN * 8);
    int* counter = (int*)(ws + (size_t)NN * DD + (size_t)NN * 12);

    prep_kernel<<<NN / 4, 256, 0, stream>>>(x, xq, sq, ap, an, counter);
    gemm_reduce_kernel<<<NTILES, 256, 0, stream>>>(xq, sq, labels, ap, an, counter, out);
}